// Round 17
// baseline (1043.230 us; speedup 1.0000x reference)
//
#include <hip/hip_runtime.h>

#define TOKENS  8192
#define IN_DIM  4096
#define OUT_DIM 12288
#define GRP     128

typedef __attribute__((ext_vector_type(8))) short  short8;    // 8 bf16
typedef __attribute__((ext_vector_type(8))) unsigned short ushort8;
typedef __attribute__((ext_vector_type(4))) float  f32x4;     // MFMA acc

#define BARRIER() asm volatile("s_barrier" ::: "memory")

__device__ __forceinline__ unsigned short f2bf(float f) {
    union { float f; unsigned int i; } x; x.f = f;
    unsigned int r = x.i + 0x7FFFu + ((x.i >> 16) & 1u);   // RNE
    return (unsigned short)(r >> 16);
}

__device__ __forceinline__ void gload_lds16(const void* g, void* l) {
    __builtin_amdgcn_global_load_lds(
        (const __attribute__((address_space(1))) void*)g,
        (__attribute__((address_space(3))) void*)l, 16, 0, 0);
}

// ---------------------------------------------------------------------------
// Merged prep kernel (r15, proven): dequant W -> bf16 (pqs folded) + cvt A.
// ---------------------------------------------------------------------------
#define DQ_BLOCKS 24576   // (OUT/2)*(IN/4)/256
#define CV_BLOCKS 16384   // TOKENS*IN/(256*8)

__global__ void prep_kernel(const int* __restrict__ wp,
                            const float* __restrict__ wsc,
                            const float* __restrict__ pqs,
                            const float* __restrict__ hid,
                            unsigned short* __restrict__ Wd,
                            unsigned short* __restrict__ Abf) {
    if (blockIdx.x < DQ_BLOCKS) {
        int idx = blockIdx.x * blockDim.x + threadIdx.x;
        int p  = idx >> 10;
        int i0 = (idx & 1023) << 2;
        int g  = i0 >> 7;
        const int4 w = *reinterpret_cast<const int4*>(wp + (size_t)p * IN_DIM + i0);
        float slo = wsc[(size_t)(2 * p)     * (IN_DIM / GRP) + g];
        float shi = wsc[(size_t)(2 * p + 1) * (IN_DIM / GRP) + g];
        float4 q = *reinterpret_cast<const float4*>(pqs + i0);
        float qf[4] = { q.x, q.y, q.z, q.w };
        int   wv[4] = { w.x, w.y, w.z, w.w };
        ushort4 lo, hi;
        unsigned short* lop = (unsigned short*)&lo;
        unsigned short* hig = (unsigned short*)&hi;
#pragma unroll
        for (int j = 0; j < 4; ++j) {
            lop[j] = f2bf((float)(( wv[j]       & 0xF) - 8) * slo * qf[j]);
            hig[j] = f2bf((float)(((wv[j] >> 4) & 0xF) - 8) * shi * qf[j]);
        }
        *reinterpret_cast<ushort4*>(Wd + (size_t)(2 * p)     * IN_DIM + i0) = lo;
        *reinterpret_cast<ushort4*>(Wd + (size_t)(2 * p + 1) * IN_DIM + i0) = hi;
    } else {
        size_t base = ((size_t)(blockIdx.x - DQ_BLOCKS) * blockDim.x + threadIdx.x) * 8;
        float4 a = *reinterpret_cast<const float4*>(hid + base);
        float4 b = *reinterpret_cast<const float4*>(hid + base + 4);
        ushort8 v;
        v[0] = f2bf(a.x); v[1] = f2bf(a.y); v[2] = f2bf(a.z); v[3] = f2bf(a.w);
        v[4] = f2bf(b.x); v[5] = f2bf(b.y); v[6] = f2bf(b.z); v[7] = f2bf(b.w);
        *reinterpret_cast<ushort8*>(Abf + base) = v;
    }
}

// ===========================================================================
// r17: A-in-LDS, B-DIRECT-FROM-GLOBAL (registers, L2/L3-served).
// Rationale: B has only 2-way intra-block reuse; staging it cost 64KB LDS
// reads + 32KB writes per tile behind barriers. Removing it cuts the serial
// LDS component ~1790->~1100 cyc/tile and deletes the entire B sync ledger.
// LDS = [buf][khalf] A-only (64KB). r15 phase skeleton (no setprio):
//  ph0: bE<-bN copy (compiler waits B(t,k0)); read A1<-k0 mh1;
//       issue B1=B(t,k1) reg loads; stage A(t+1,k1)->lds[q][1]; MFMA(aE,bE);
//       BAR   [A(t,k1) publish: drained by the pre-MFMA B(t,k0) wait
//              (B issued t-1-ph2 AFTER A(t,k1)@t-1-ph0), BAR publishes]
//  ph1: read aE<-k1 mh0; MFMA(A1,bE); BAR
//  ph2: read A1<-k1 mh1; stage A(t+2,k0)->lds[p][0] THEN issue
//       bN=B(t+1,k0) (order matters: B younger => t+1-ph0's B-wait drains
//       both A stages); MFMA(aE,B1); BAR
//  ph3: entry reads aE<-lds[q][0] (A(t+1,k0), published: drained at t-ph0
//       B-wait since B(t,k0)@t-1-ph2 is younger, + 3 BARs); MFMA(A1,B1); BAR
// WAR audit: every overwritten A region's last ds_read is consumed by an
// MFMA (compiler lgkm wait) >=1 barrier before the overwriting DMA issues:
//  ph0 stage lds[q][1] vs (t-1,k1) reads @t-1-ph1/ph2 (consumed <= t-1-ph3
//  MFMA) OK; ph2 stage lds[p][0] vs (t,k0) reads @t-1-ph3/ph0 (consumed <=
//  ph1 MFMA < ph1-end BAR) OK. No manual vmcnt in the loop; prologue
//  vmcnt(4) is reorder-proof (drains A(0,k0) whether or not B hoists).
// ===========================================================================
#define BM 256
#define BN 256
#define BK 64
#define NT (IN_DIM / BK)   // 64

__device__ __forceinline__ void stage_chunk(const unsigned short* gbase, int rowbase,
                                            int t, int kh, char* region, int tid) {
#pragma unroll
    for (int c = 0; c < 2; ++c) {
        int off  = c * 8192 + tid * 16;               // linear LDS dest
        int row  = off >> 6;                          // 64B per row
        int slot = (off >> 4) & 3;
        int col  = t * 64 + kh * 32 + ((slot ^ ((row >> 1) & 3)) << 3); // inverse swz
        gload_lds16(gbase + (size_t)(rowbase + row) * IN_DIM + col, region + off);
    }
}

__global__ __launch_bounds__(512, 2) void gemm8p_kernel(
    const unsigned short* __restrict__ A,   // [TOKENS][IN] bf16 (LDS-staged)
    const unsigned short* __restrict__ Bp,  // [OUT][IN] bf16 (direct global)
    float* __restrict__ C) {                // [TOKENS][OUT] f32

    __shared__ char lds[2][2][16384];       // [buf][khalf] A-only = 64KB

    const int tid  = threadIdx.x;
    const int lane = tid & 63;
    const int wid  = tid >> 6;
    const int wm   = wid >> 2;              // 0..1
    const int wn   = wid & 3;               // 0..3
    const int lq   = lane & 15;
    const int lr   = lane >> 4;             // 0..3
    const int sw   = (lr ^ ((lq >> 1) & 3)) << 4;   // swizzled slot byte offset

    // grid 1536 = 8 * 192: bijective XCD swizzle
    int bid = blockIdx.x;
    int swz = (bid & 7) * 192 + (bid >> 3);
    const int brow = (swz / (OUT_DIM / BN)) * BM;
    const int bcol = (swz % (OUT_DIM / BN)) * BN;

    // B frag global base: frag (n, kh) at tile t =
    //   Bp[(bcol + wn*64 + n*16 + lq) * IN + t*64 + kh*32 + lr*8], 16B/lane.
    const unsigned short* Bbase = Bp + (size_t)(bcol + wn * 64 + lq) * IN_DIM + lr * 8;

    f32x4 acc[8][4] = {};
    short8 aE[4], A1[4], bE[4], bN[4], B1[4];

    // ---- prologue: A(0,k0), A(0,k1), A(1,k0) DMA; issue bN=B(0,k0) ----
    stage_chunk(A, brow, 0, 0, &lds[0][0][0], tid);
    stage_chunk(A, brow, 0, 1, &lds[0][1][0], tid);
    stage_chunk(A, brow, 1, 0, &lds[1][0][0], tid);
#pragma unroll
    for (int n = 0; n < 4; ++n)
        bN[n] = *reinterpret_cast<const short8*>(Bbase + (size_t)(n * 16) * IN_DIM + 0);
    asm volatile("s_waitcnt vmcnt(4)" ::: "memory");   // A(0,k0) landed (reorder-proof)
    BARRIER();
#pragma unroll
    for (int m = 0; m < 4; ++m)
        aE[m] = *reinterpret_cast<const short8*>(
            &lds[0][0][(wm * 128 + m * 16 + lq) * 64 + sw]);

    for (int t = 0; t < NT; ++t) {
        const int p = t & 1, q = p ^ 1;

        // ---------- phase 0: MFMA(aE k0 mh0, bE k0) ----------
#pragma unroll
        for (int n = 0; n < 4; ++n) bE[n] = bN[n];   // forces wait for B(t,k0)
#pragma unroll
        for (int m = 0; m < 4; ++m)
            A1[m] = *reinterpret_cast<const short8*>(
                &lds[p][0][(wm * 128 + (m + 4) * 16 + lq) * 64 + sw]);
#pragma unroll
        for (int n = 0; n < 4; ++n)                   // issue B1 = B(t,k1)
            B1[n] = *reinterpret_cast<const short8*>(
                Bbase + (size_t)(n * 16) * IN_DIM + t * 64 + 32);
        if (t + 1 < NT) stage_chunk(A, brow, t + 1, 1, &lds[q][1][0], tid);
#pragma unroll
        for (int m = 0; m < 4; ++m)
#pragma unroll
            for (int n = 0; n < 4; ++n)
                acc[m][n] = __builtin_amdgcn_mfma_f32_16x16x32_bf16(
                    aE[m], bE[n], acc[m][n], 0, 0, 0);
        BARRIER();

        // ---------- phase 1: MFMA(A1 k0 mh1, bE) ; read aE<-k1 mh0 ----------
#pragma unroll
        for (int m = 0; m < 4; ++m)
            aE[m] = *reinterpret_cast<const short8*>(
                &lds[p][1][(wm * 128 + m * 16 + lq) * 64 + sw]);
#pragma unroll
        for (int m = 0; m < 4; ++m)
#pragma unroll
            for (int n = 0; n < 4; ++n)
                acc[m + 4][n] = __builtin_amdgcn_mfma_f32_16x16x32_bf16(
                    A1[m], bE[n], acc[m + 4][n], 0, 0, 0);
        BARRIER();

        // ---------- phase 2: MFMA(aE k1 mh0, B1) ; read A1<-k1 mh1 ----------
#pragma unroll
        for (int m = 0; m < 4; ++m)
            A1[m] = *reinterpret_cast<const short8*>(
                &lds[p][1][(wm * 128 + (m + 4) * 16 + lq) * 64 + sw]);
        if (t + 2 < NT) stage_chunk(A, brow, t + 2, 0, &lds[p][0][0], tid);
        if (t + 1 < NT) {                             // issue bN = B(t+1,k0)
#pragma unroll
            for (int n = 0; n < 4; ++n)
                bN[n] = *reinterpret_cast<const short8*>(
                    Bbase + (size_t)(n * 16) * IN_DIM + (t + 1) * 64);
        }
#pragma unroll
        for (int m = 0; m < 4; ++m)
#pragma unroll
            for (int n = 0; n < 4; ++n)
                acc[m][n] = __builtin_amdgcn_mfma_f32_16x16x32_bf16(
                    aE[m], B1[n], acc[m][n], 0, 0, 0);
        BARRIER();

        // ---------- phase 3: MFMA(A1 k1 mh1, B1) ; entry reads for t+1 ------
        if (t + 1 < NT) {
#pragma unroll
            for (int m = 0; m < 4; ++m)
                aE[m] = *reinterpret_cast<const short8*>(
                    &lds[q][0][(wm * 128 + m * 16 + lq) * 64 + sw]);
        }
#pragma unroll
        for (int m = 0; m < 4; ++m)
#pragma unroll
            for (int n = 0; n < 4; ++n)
                acc[m + 4][n] = __builtin_amdgcn_mfma_f32_16x16x32_bf16(
                    A1[m], B1[n], acc[m + 4][n], 0, 0, 0);
        BARRIER();
    }

    // ---- epilogue: C/D layout col=lane&15, row=(lane>>4)*4+j; plain stores
    // (L2 write-combines; nt-scalar inflated WRITE 25%, r7) ----
#pragma unroll
    for (int m = 0; m < 8; ++m)
#pragma unroll
        for (int n = 0; n < 4; ++n)
#pragma unroll
            for (int j = 0; j < 4; ++j) {
                int row = brow + wm * 128 + m * 16 + lr * 4 + j;
                int col = bcol + wn * 64 + n * 16 + lq;
                C[(size_t)row * OUT_DIM + col] = acc[m][n][j];
            }
}

// ---------------------------------------------------------------------------
// Fallback (ws too small): round-4 proven 128x128 2-phase kernel.
// ---------------------------------------------------------------------------
template <bool CONV_A, bool FUSED_B>
__global__ __launch_bounds__(256) void gemm_fb_kernel(
    const void* __restrict__ Ap, const unsigned short* __restrict__ Bd,
    const int* __restrict__ Wp, const float* __restrict__ wsc,
    const float* __restrict__ pqs, float* __restrict__ C) {
    __shared__ short sA[128 * 64];
    __shared__ short sB[128 * 64];
    const int tid  = threadIdx.x;
    const int lane = tid & 63;
    const int w    = tid >> 6;
    const int wr   = w >> 1, wc = w & 1;
    const int lr   = lane >> 4;
    const int lq   = lane & 15;
    const int nbn = OUT_DIM / 128;
    int bid = blockIdx.x;
    int swzb = (bid & 7) * ((TOKENS / 128) * nbn / 8) + (bid >> 3);
    const int brow = (swzb / nbn) * 128;
    const int bcol = (swzb % nbn) * 128;
    f32x4 acc[4][4] = {};
    for (int k0 = 0; k0 < IN_DIM; k0 += 64) {
#pragma unroll
        for (int c = 0; c < 4; ++c) {
            int off  = c * 4096 + tid * 16;
            int r    = off >> 7;
            if constexpr (CONV_A) {
                int e = (off & 127) >> 1;
                const float* src = (const float*)Ap + (size_t)(brow + r) * IN_DIM + k0 + e;
                float4 f0 = *reinterpret_cast<const float4*>(src);
                float4 f1 = *reinterpret_cast<const float4*>(src + 4);
                ushort8 v;
                v[0] = f2bf(f0.x); v[1] = f2bf(f0.y); v[2] = f2bf(f0.z); v[3] = f2bf(f0.w);
                v[4] = f2bf(f1.x); v[5] = f2bf(f1.y); v[6] = f2bf(f1.z); v[7] = f2bf(f1.w);
                *reinterpret_cast<ushort8*>((char*)sA + off) = v;
            } else {
                int colb = off & 127;
                gload_lds16((const char*)Ap + ((size_t)(brow + r) * IN_DIM + k0) * 2 + colb,
                            (char*)sA + off);
            }
            if constexpr (!FUSED_B) {
                int colb = off & 127;
                gload_lds16((const char*)Bd + ((size_t)(bcol + r) * IN_DIM + k0) * 2 + colb,
                            (char*)sB + off);
            }
        }
        if constexpr (FUSED_B) {
#pragma unroll
            for (int c = 0; c < 4; ++c) {
                int pr = c * 16 + (tid >> 4);
                int i0 = (tid & 15) * 4;
                int gp = (bcol >> 1) + pr;
                int gk = k0 + i0;
                int4 wv = *reinterpret_cast<const int4*>(Wp + (size_t)gp * IN_DIM + gk);
                int g = gk >> 7;
                float slo = wsc[(size_t)(2 * gp)     * (IN_DIM / GRP) + g];
                float shi = wsc[(size_t)(2 * gp + 1) * (IN_DIM / GRP) + g];
                float4 qv = *reinterpret_cast<const float4*>(pqs + gk);
                float qf[4] = { qv.x, qv.y, qv.z, qv.w };
                int wi[4] = { wv.x, wv.y, wv.z, wv.w };
                ushort4 lo, hi;
                unsigned short* lop = (unsigned short*)&lo;
                unsigned short* hig = (unsigned short*)&hi;
#pragma unroll
                for (int j = 0; j < 4; ++j) {
                    lop[j] = f2bf((float)(( wi[j]       & 0xF) - 8) * slo * qf[j]);
                    hig[j] = f2bf((float)(((wi[j] >> 4) & 0xF) - 8) * shi * qf[j]);
                }
                *reinterpret_cast<ushort4*>(&sB[(2 * pr)     * 64 + i0]) = lo;
                *reinterpret_cast<ushort4*>(&sB[(2 * pr + 1) * 64 + i0]) = hi;
            }
        }
        __syncthreads();
#pragma unroll
        for (int kk = 0; kk < 64; kk += 32) {
            int ko = kk + lr * 8;
            short8 af[4], bf[4];
#pragma unroll
            for (int m = 0; m < 4; ++m)
                af[m] = *reinterpret_cast<const short8*>(&sA[(wr * 64 + m * 16 + lq) * 64 + ko]);
#pragma unroll
            for (int n = 0; n < 4; ++n)
                bf[n] = *reinterpret_cast<const short8*>(&sB[(wc * 64 + n * 16 + lq) * 64 + ko]);
#pragma unroll
            for (int m = 0; m < 4; ++m)
#pragma unroll
                for (int n = 0; n < 4; ++n)
                    acc[m][n] = __builtin_amdgcn_mfma_f32_16x16x32_bf16(
                        af[m], bf[n], acc[m][n], 0, 0, 0);
        }
        __syncthreads();
    }
#pragma unroll
    for (int m = 0; m < 4; ++m)
#pragma unroll
        for (int n = 0; n < 4; ++n)
#pragma unroll
            for (int j = 0; j < 4; ++j) {
                int row = brow + wr * 64 + m * 16 + lr * 4 + j;
                int col = bcol + wc * 64 + n * 16 + lq;
                C[(size_t)row * OUT_DIM + col] = acc[m][n][j];
            }
}

extern "C" void kernel_launch(void* const* d_in, const int* in_sizes, int n_in,
                              void* d_out, int out_size, void* d_ws, size_t ws_size,
                              hipStream_t stream) {
    // Resolve inputs by element count (all distinct)
    const void* p_hidden = nullptr; const void* p_weight = nullptr;
    const void* p_wscale = nullptr; const void* p_pqs = nullptr;
    for (int i = 0; i < n_in; ++i) {
        switch (in_sizes[i]) {
            case 33554432: p_hidden = d_in[i]; break;
            case 25165824: p_weight = d_in[i]; break;
            case 393216:   p_wscale = d_in[i]; break;
            case 4096:     p_pqs    = d_in[i]; break;
            default: break;
        }
    }
    if (!p_hidden || !p_weight || !p_wscale || !p_pqs) {
        p_hidden = d_in[0]; p_weight = d_in[1]; p_wscale = d_in[2]; p_pqs = d_in[3];
    }
    const float* hidden = (const float*)p_hidden;
    const int*   weight = (const int*)p_weight;
    const float* wscale = (const float*)p_wscale;
    const float* pqs    = (const float*)p_pqs;
    float*       out    = (float*)d_out;

    const size_t wd_bytes = (size_t)OUT_DIM * IN_DIM * 2;     // 96 MB bf16 W
    const size_t ab_bytes = (size_t)TOKENS * IN_DIM * 2;      // 64 MB bf16 A

    if (ws_size >= wd_bytes + ab_bytes) {
        unsigned short* Wd  = (unsigned short*)d_ws;
        unsigned short* Abf = (unsigned short*)((char*)d_ws + wd_bytes);
        prep_kernel<<<DQ_BLOCKS + CV_BLOCKS, 256, 0, stream>>>(
            weight, wscale, pqs, hidden, Wd, Abf);
        gemm8p_kernel<<<(TOKENS / BM) * (OUT_DIM / BN), 512, 0, stream>>>(Abf, Wd, out);
    } else if (ws_size >= wd_bytes) {
        unsigned short* Wd = (unsigned short*)d_ws;
        prep_kernel<<<DQ_BLOCKS, 256, 0, stream>>>(
            weight, wscale, pqs, hidden, Wd, nullptr);
        gemm_fb_kernel<true, false><<<(TOKENS / 128) * (OUT_DIM / 128), 256, 0, stream>>>(
            hidden, Wd, nullptr, nullptr, nullptr, out);
    } else {
        gemm_fb_kernel<true, true><<<(TOKENS / 128) * (OUT_DIM / 128), 256, 0, stream>>>(
            hidden, nullptr, weight, wscale, pqs, out);
    }
}

// Round 18
// 792.032 us; speedup vs baseline: 1.3172x; 1.3172x over previous
//
#include <hip/hip_runtime.h>

#define TOKENS  8192
#define IN_DIM  4096
#define OUT_DIM 12288
#define GRP     128

typedef __attribute__((ext_vector_type(8))) short  short8;    // 8 bf16
typedef __attribute__((ext_vector_type(8))) unsigned short ushort8;
typedef __attribute__((ext_vector_type(4))) float  f32x4;     // MFMA acc

#define BARRIER() asm volatile("s_barrier" ::: "memory")

__device__ __forceinline__ unsigned short f2bf(float f) {
    union { float f; unsigned int i; } x; x.f = f;
    unsigned int r = x.i + 0x7FFFu + ((x.i >> 16) & 1u);   // RNE
    return (unsigned short)(r >> 16);
}

__device__ __forceinline__ void gload_lds16(const void* g, void* l) {
    __builtin_amdgcn_global_load_lds(
        (const __attribute__((address_space(1))) void*)g,
        (__attribute__((address_space(3))) void*)l, 16, 0, 0);
}

// ---------------------------------------------------------------------------
// Merged prep kernel: blocks [0, 24576) dequant packed int4 -> Wd bf16
// (pqs folded in); blocks [24576, 40960) convert hidden f32 -> Abf bf16.
// ---------------------------------------------------------------------------
#define DQ_BLOCKS 24576   // (OUT/2)*(IN/4)/256
#define CV_BLOCKS 16384   // TOKENS*IN/(256*8)

__global__ void prep_kernel(const int* __restrict__ wp,
                            const float* __restrict__ wsc,
                            const float* __restrict__ pqs,
                            const float* __restrict__ hid,
                            unsigned short* __restrict__ Wd,
                            unsigned short* __restrict__ Abf) {
    if (blockIdx.x < DQ_BLOCKS) {
        int idx = blockIdx.x * blockDim.x + threadIdx.x;
        int p  = idx >> 10;
        int i0 = (idx & 1023) << 2;
        int g  = i0 >> 7;
        const int4 w = *reinterpret_cast<const int4*>(wp + (size_t)p * IN_DIM + i0);
        float slo = wsc[(size_t)(2 * p)     * (IN_DIM / GRP) + g];
        float shi = wsc[(size_t)(2 * p + 1) * (IN_DIM / GRP) + g];
        float4 q = *reinterpret_cast<const float4*>(pqs + i0);
        float qf[4] = { q.x, q.y, q.z, q.w };
        int   wv[4] = { w.x, w.y, w.z, w.w };
        ushort4 lo, hi;
        unsigned short* lop = (unsigned short*)&lo;
        unsigned short* hig = (unsigned short*)&hi;
#pragma unroll
        for (int j = 0; j < 4; ++j) {
            lop[j] = f2bf((float)(( wv[j]       & 0xF) - 8) * slo * qf[j]);
            hig[j] = f2bf((float)(((wv[j] >> 4) & 0xF) - 8) * shi * qf[j]);
        }
        *reinterpret_cast<ushort4*>(Wd + (size_t)(2 * p)     * IN_DIM + i0) = lo;
        *reinterpret_cast<ushort4*>(Wd + (size_t)(2 * p + 1) * IN_DIM + i0) = hi;
    } else {
        size_t base = ((size_t)(blockIdx.x - DQ_BLOCKS) * blockDim.x + threadIdx.x) * 8;
        float4 a = *reinterpret_cast<const float4*>(hid + base);
        float4 b = *reinterpret_cast<const float4*>(hid + base + 4);
        ushort8 v;
        v[0] = f2bf(a.x); v[1] = f2bf(a.y); v[2] = f2bf(a.z); v[3] = f2bf(a.w);
        v[4] = f2bf(b.x); v[5] = f2bf(b.y); v[6] = f2bf(b.z); v[7] = f2bf(b.w);
        *reinterpret_cast<ushort8*>(Abf + base) = v;
    }
}

// ===========================================================================
// r18 = r15 verbatim (best-known-good: 798.66 µs total, GEMM ~760 µs,
// MfmaUtil 58-60%, 0 bank conflicts). 256x256 8-phase, r9 read-ahead
// schedule, no setprio (r15 A/B: +7pts MfmaUtil vs r11).
// Read schedule (per wave/tile): ph3(t-1) entry aE,bE (t,k0) [8];
// ph0 A1 k0 mh1 [4]; ph1 aE k1 mh0 + B1 k1 [8]; ph2 A1 k1 mh1 [4].
// Stages: ph0 A(t+1,k1); ph1 B(t+1,k1); ph2 A(t+2,k0); ph3 B(t+2,k0).
// Publishes (per-wave counted vmcnt IMMEDIATELY before a barrier, r6 rule):
//   ph0-end (t,k1) vmcnt(6) [tail 0]; ph2-end (t+1,k0) vmcnt(6) [tails 4/skip].
// WAR audit: every overwrite DMA issues >=1 barrier after its region's last
// reader phase (compiler emits counted lgkm for MFMA deps).
// ===========================================================================
#define BM 256
#define BN 256
#define BK 64
#define NT (IN_DIM / BK)   // 64

__device__ __forceinline__ void stage_chunk(const unsigned short* gbase, int rowbase,
                                            int t, int kh, char* region, int tid) {
#pragma unroll
    for (int c = 0; c < 2; ++c) {
        int off  = c * 8192 + tid * 16;               // linear LDS dest
        int row  = off >> 6;                          // 64B per row
        int slot = (off >> 4) & 3;
        int col  = t * 64 + kh * 32 + ((slot ^ ((row >> 1) & 3)) << 3); // inverse swz
        gload_lds16(gbase + (size_t)(rowbase + row) * IN_DIM + col, region + off);
    }
}

__global__ __launch_bounds__(512, 2) void gemm8p_kernel(
    const unsigned short* __restrict__ A,   // [TOKENS][IN] bf16
    const unsigned short* __restrict__ B,   // [OUT][IN] bf16
    float* __restrict__ C) {                // [TOKENS][OUT] f32

    __shared__ char lds[2][2][2][16384];    // [buf][mat A=0/B=1][khalf][bytes]

    const int tid  = threadIdx.x;
    const int lane = tid & 63;
    const int wid  = tid >> 6;
    const int wm   = wid >> 2;              // 0..1
    const int wn   = wid & 3;               // 0..3
    const int lq   = lane & 15;
    const int lr   = lane >> 4;             // 0..3
    const int sw   = (lr ^ ((lq >> 1) & 3)) << 4;   // swizzled slot byte offset

    // grid 1536 = 8 * 192: bijective XCD swizzle
    int bid = blockIdx.x;
    int swz = (bid & 7) * 192 + (bid >> 3);
    const int brow = (swz / (OUT_DIM / BN)) * BM;
    const int bcol = (swz % (OUT_DIM / BN)) * BN;

    f32x4 acc[8][4] = {};
    short8 aE[4], A1[4], bE[4], B1[4];

    // ---- prologue: FIFO order A0k0,B0k0,A0k1,B0k1,A1k0,B1k0 (12 loads) ----
    stage_chunk(A, brow, 0, 0, &lds[0][0][0][0], tid);
    stage_chunk(B, bcol, 0, 0, &lds[0][1][0][0], tid);
    stage_chunk(A, brow, 0, 1, &lds[0][0][1][0], tid);
    stage_chunk(B, bcol, 0, 1, &lds[0][1][1][0], tid);
    stage_chunk(A, brow, 1, 0, &lds[1][0][0][0], tid);
    stage_chunk(B, bcol, 1, 0, &lds[1][1][0][0], tid);
    asm volatile("s_waitcnt vmcnt(8)" ::: "memory");   // (0,k0) landed
    BARRIER();
    // entry reads for t=0 (normally done in ph3 of t-1)
#pragma unroll
    for (int m = 0; m < 4; ++m)
        aE[m] = *reinterpret_cast<const short8*>(
            &lds[0][0][0][(wm * 128 + m * 16 + lq) * 64 + sw]);
#pragma unroll
    for (int n = 0; n < 4; ++n)
        bE[n] = *reinterpret_cast<const short8*>(
            &lds[0][1][0][(wn * 64 + n * 16 + lq) * 64 + sw]);

    for (int t = 0; t < NT; ++t) {
        const int p = t & 1, q = p ^ 1;

        // ---------- phase 0: MFMA(aE k0 mh0, bE) ; read A1<-k0 mh1 ----------
#pragma unroll
        for (int m = 0; m < 4; ++m)
            A1[m] = *reinterpret_cast<const short8*>(
                &lds[p][0][0][(wm * 128 + (m + 4) * 16 + lq) * 64 + sw]);
        if (t + 1 < NT) stage_chunk(A, brow, t + 1, 1, &lds[q][0][1][0], tid);
#pragma unroll
        for (int m = 0; m < 4; ++m)
#pragma unroll
            for (int n = 0; n < 4; ++n)
                acc[m][n] = __builtin_amdgcn_mfma_f32_16x16x32_bf16(
                    aE[m], bE[n], acc[m][n], 0, 0, 0);
        // publish (t,k1)
        if (t + 1 < NT) { asm volatile("s_waitcnt vmcnt(6)" ::: "memory"); }
        else            { asm volatile("s_waitcnt vmcnt(0)" ::: "memory"); }
        BARRIER();

        // ---------- phase 1: MFMA(A1 k0 mh1, bE) ; read aE<-k1 mh0, B1<-k1 --
#pragma unroll
        for (int m = 0; m < 4; ++m)
            aE[m] = *reinterpret_cast<const short8*>(
                &lds[p][0][1][(wm * 128 + m * 16 + lq) * 64 + sw]);
#pragma unroll
        for (int n = 0; n < 4; ++n)
            B1[n] = *reinterpret_cast<const short8*>(
                &lds[p][1][1][(wn * 64 + n * 16 + lq) * 64 + sw]);
        if (t + 1 < NT) stage_chunk(B, bcol, t + 1, 1, &lds[q][1][1][0], tid);
#pragma unroll
        for (int m = 0; m < 4; ++m)
#pragma unroll
            for (int n = 0; n < 4; ++n)
                acc[m + 4][n] = __builtin_amdgcn_mfma_f32_16x16x32_bf16(
                    A1[m], bE[n], acc[m + 4][n], 0, 0, 0);
        BARRIER();

        // ---------- phase 2: MFMA(aE k1 mh0, B1) ; read A1<-k1 mh1 ----------
#pragma unroll
        for (int m = 0; m < 4; ++m)
            A1[m] = *reinterpret_cast<const short8*>(
                &lds[p][0][1][(wm * 128 + (m + 4) * 16 + lq) * 64 + sw]);
        if (t + 2 < NT) stage_chunk(A, brow, t + 2, 0, &lds[p][0][0][0], tid);
#pragma unroll
        for (int m = 0; m < 4; ++m)
#pragma unroll
            for (int n = 0; n < 4; ++n)
                acc[m][n] = __builtin_amdgcn_mfma_f32_16x16x32_bf16(
                    aE[m], B1[n], acc[m][n], 0, 0, 0);
        // publish (t+1,k0)
        if (t + 1 < NT) {
            if (t + 2 < NT) { asm volatile("s_waitcnt vmcnt(6)" ::: "memory"); }
            else            { asm volatile("s_waitcnt vmcnt(4)" ::: "memory"); }
        }
        BARRIER();

        // ---------- phase 3: MFMA(A1 k1 mh1, B1) ; entry reads for t+1 ------
        if (t + 1 < NT) {
#pragma unroll
            for (int m = 0; m < 4; ++m)
                aE[m] = *reinterpret_cast<const short8*>(
                    &lds[q][0][0][(wm * 128 + m * 16 + lq) * 64 + sw]);
#pragma unroll
            for (int n = 0; n < 4; ++n)
                bE[n] = *reinterpret_cast<const short8*>(
                    &lds[q][1][0][(wn * 64 + n * 16 + lq) * 64 + sw]);
        }
        if (t + 2 < NT) stage_chunk(B, bcol, t + 2, 0, &lds[p][1][0][0], tid);
#pragma unroll
        for (int m = 0; m < 4; ++m)
#pragma unroll
            for (int n = 0; n < 4; ++n)
                acc[m + 4][n] = __builtin_amdgcn_mfma_f32_16x16x32_bf16(
                    A1[m], B1[n], acc[m + 4][n], 0, 0, 0);
        BARRIER();
    }

    // ---- epilogue: C/D layout col=lane&15, row=(lane>>4)*4+j; plain stores
    // (L2 write-combines; nt-scalar inflated WRITE 25%, r7) ----
#pragma unroll
    for (int m = 0; m < 8; ++m)
#pragma unroll
        for (int n = 0; n < 4; ++n)
#pragma unroll
            for (int j = 0; j < 4; ++j) {
                int row = brow + wm * 128 + m * 16 + lr * 4 + j;
                int col = bcol + wn * 64 + n * 16 + lq;
                C[(size_t)row * OUT_DIM + col] = acc[m][n][j];
            }
}

// ---------------------------------------------------------------------------
// Fallback (ws too small): round-4 proven 128x128 2-phase kernel.
// ---------------------------------------------------------------------------
template <bool CONV_A, bool FUSED_B>
__global__ __launch_bounds__(256) void gemm_fb_kernel(
    const void* __restrict__ Ap, const unsigned short* __restrict__ Bd,
    const int* __restrict__ Wp, const float* __restrict__ wsc,
    const float* __restrict__ pqs, float* __restrict__ C) {
    __shared__ short sA[128 * 64];
    __shared__ short sB[128 * 64];
    const int tid  = threadIdx.x;
    const int lane = tid & 63;
    const int w    = tid >> 6;
    const int wr   = w >> 1, wc = w & 1;
    const int lr   = lane >> 4;
    const int lq   = lane & 15;
    const int nbn = OUT_DIM / 128;
    int bid = blockIdx.x;
    int swzb = (bid & 7) * ((TOKENS / 128) * nbn / 8) + (bid >> 3);
    const int brow = (swzb / nbn) * 128;
    const int bcol = (swzb % nbn) * 128;
    f32x4 acc[4][4] = {};
    for (int k0 = 0; k0 < IN_DIM; k0 += 64) {
#pragma unroll
        for (int c = 0; c < 4; ++c) {
            int off  = c * 4096 + tid * 16;
            int r    = off >> 7;
            if constexpr (CONV_A) {
                int e = (off & 127) >> 1;
                const float* src = (const float*)Ap + (size_t)(brow + r) * IN_DIM + k0 + e;
                float4 f0 = *reinterpret_cast<const float4*>(src);
                float4 f1 = *reinterpret_cast<const float4*>(src + 4);
                ushort8 v;
                v[0] = f2bf(f0.x); v[1] = f2bf(f0.y); v[2] = f2bf(f0.z); v[3] = f2bf(f0.w);
                v[4] = f2bf(f1.x); v[5] = f2bf(f1.y); v[6] = f2bf(f1.z); v[7] = f2bf(f1.w);
                *reinterpret_cast<ushort8*>((char*)sA + off) = v;
            } else {
                int colb = off & 127;
                gload_lds16((const char*)Ap + ((size_t)(brow + r) * IN_DIM + k0) * 2 + colb,
                            (char*)sA + off);
            }
            if constexpr (!FUSED_B) {
                int colb = off & 127;
                gload_lds16((const char*)Bd + ((size_t)(bcol + r) * IN_DIM + k0) * 2 + colb,
                            (char*)sB + off);
            }
        }
        if constexpr (FUSED_B) {
#pragma unroll
            for (int c = 0; c < 4; ++c) {
                int pr = c * 16 + (tid >> 4);
                int i0 = (tid & 15) * 4;
                int gp = (bcol >> 1) + pr;
                int gk = k0 + i0;
                int4 wv = *reinterpret_cast<const int4*>(Wp + (size_t)gp * IN_DIM + gk);
                int g = gk >> 7;
                float slo = wsc[(size_t)(2 * gp)     * (IN_DIM / GRP) + g];
                float shi = wsc[(size_t)(2 * gp + 1) * (IN_DIM / GRP) + g];
                float4 qv = *reinterpret_cast<const float4*>(pqs + gk);
                float qf[4] = { qv.x, qv.y, qv.z, qv.w };
                int wi[4] = { wv.x, wv.y, wv.z, wv.w };
                ushort4 lo, hi;
                unsigned short* lop = (unsigned short*)&lo;
                unsigned short* hig = (unsigned short*)&hi;
#pragma unroll
                for (int j = 0; j < 4; ++j) {
                    lop[j] = f2bf((float)(( wi[j]       & 0xF) - 8) * slo * qf[j]);
                    hig[j] = f2bf((float)(((wi[j] >> 4) & 0xF) - 8) * shi * qf[j]);
                }
                *reinterpret_cast<ushort4*>(&sB[(2 * pr)     * 64 + i0]) = lo;
                *reinterpret_cast<ushort4*>(&sB[(2 * pr + 1) * 64 + i0]) = hi;
            }
        }
        __syncthreads();
#pragma unroll
        for (int kk = 0; kk < 64; kk += 32) {
            int ko = kk + lr * 8;
            short8 af[4], bf[4];
#pragma unroll
            for (int m = 0; m < 4; ++m)
                af[m] = *reinterpret_cast<const short8*>(&sA[(wr * 64 + m * 16 + lq) * 64 + ko]);
#pragma unroll
            for (int n = 0; n < 4; ++n)
                bf[n] = *reinterpret_cast<const short8*>(&sB[(wc * 64 + n * 16 + lq) * 64 + ko]);
#pragma unroll
            for (int m = 0; m < 4; ++m)
#pragma unroll
                for (int n = 0; n < 4; ++n)
                    acc[m][n] = __builtin_amdgcn_mfma_f32_16x16x32_bf16(
                        af[m], bf[n], acc[m][n], 0, 0, 0);
        }
        __syncthreads();
    }
#pragma unroll
    for (int m = 0; m < 4; ++m)
#pragma unroll
        for (int n = 0; n < 4; ++n)
#pragma unroll
            for (int j = 0; j < 4; ++j) {
                int row = brow + wr * 64 + m * 16 + lr * 4 + j;
                int col = bcol + wc * 64 + n * 16 + lq;
                C[(size_t)row * OUT_DIM + col] = acc[m][n][j];
            }
}

extern "C" void kernel_launch(void* const* d_in, const int* in_sizes, int n_in,
                              void* d_out, int out_size, void* d_ws, size_t ws_size,
                              hipStream_t stream) {
    // Resolve inputs by element count (all distinct)
    const void* p_hidden = nullptr; const void* p_weight = nullptr;
    const void* p_wscale = nullptr; const void* p_pqs = nullptr;
    for (int i = 0; i < n_in; ++i) {
        switch (in_sizes[i]) {
            case 33554432: p_hidden = d_in[i]; break;
            case 25165824: p_weight = d_in[i]; break;
            case 393216:   p_wscale = d_in[i]; break;
            case 4096:     p_pqs    = d_in[i]; break;
            default: break;
        }
    }
    if (!p_hidden || !p_weight || !p_wscale || !p_pqs) {
        p_hidden = d_in[0]; p_weight = d_in[1]; p_wscale = d_in[2]; p_pqs = d_in[3];
    }
    const float* hidden = (const float*)p_hidden;
    const int*   weight = (const int*)p_weight;
    const float* wscale = (const float*)p_wscale;
    const float* pqs    = (const float*)p_pqs;
    float*       out    = (float*)d_out;

    const size_t wd_bytes = (size_t)OUT_DIM * IN_DIM * 2;     // 96 MB bf16 W
    const size_t ab_bytes = (size_t)TOKENS * IN_DIM * 2;      // 64 MB bf16 A

    if (ws_size >= wd_bytes + ab_bytes) {
        unsigned short* Wd  = (unsigned short*)d_ws;
        unsigned short* Abf = (unsigned short*)((char*)d_ws + wd_bytes);
        prep_kernel<<<DQ_BLOCKS + CV_BLOCKS, 256, 0, stream>>>(
            weight, wscale, pqs, hidden, Wd, Abf);
        gemm8p_kernel<<<(TOKENS / BM) * (OUT_DIM / BN), 512, 0, stream>>>(Abf, Wd, out);
    } else if (ws_size >= wd_bytes) {
        unsigned short* Wd = (unsigned short*)d_ws;
        prep_kernel<<<DQ_BLOCKS, 256, 0, stream>>>(
            weight, wscale, pqs, hidden, Wd, nullptr);
        gemm_fb_kernel<true, false><<<(TOKENS / 128) * (OUT_DIM / 128), 256, 0, stream>>>(
            hidden, Wd, nullptr, nullptr, nullptr, out);
    } else {
        gemm_fb_kernel<true, true><<<(TOKENS / 128) * (OUT_DIM / 128), 256, 0, stream>>>(
            hidden, nullptr, weight, wscale, pqs, out);
    }
}